// Round 1
// baseline (938.721 us; speedup 1.0000x reference)
//
#include <hip/hip_runtime.h>

#define NN 50000      // nodes
#define NE 800000     // edges
#define DIM 128       // feature dim (D == H)
#define NG 64         // graphs
#define NOUT 10       // output dim

// ---------------------------------------------------------------- counting
__global__ void count_kernel(const int* __restrict__ ei, const int* __restrict__ batch,
                             int* __restrict__ deg_cnt, int* __restrict__ gcnt) {
    int i = blockIdx.x * blockDim.x + threadIdx.x;
    int stride = gridDim.x * blockDim.x;
    const int* dst = ei + NE;
    for (int e = i; e < NE; e += stride) atomicAdd(&deg_cnt[dst[e]], 1);
    for (int k = i; k < NN; k += stride) atomicAdd(&gcnt[batch[k]], 1);
}

__global__ void dinv_kernel(const int* __restrict__ deg_cnt, float* __restrict__ dinv) {
    int i = blockIdx.x * blockDim.x + threadIdx.x;
    if (i < NN) dinv[i] = 1.0f / sqrtf((float)deg_cnt[i] + 1.0f);
}

// ---------------------------------------------------------------- scan (3-phase)
__global__ void scan1_kernel(const int* __restrict__ cnt, int* __restrict__ rowoff,
                             int* __restrict__ bsum) {
    __shared__ int s[256];
    int tx = threadIdx.x;
    int idx = blockIdx.x * 256 + tx;
    int v = (idx < NN) ? cnt[idx] : 0;
    s[tx] = v;
    __syncthreads();
    #pragma unroll
    for (int off = 1; off < 256; off <<= 1) {
        int t = (tx >= off) ? s[tx - off] : 0;
        __syncthreads();
        s[tx] += t;
        __syncthreads();
    }
    if (idx < NN) rowoff[idx] = s[tx] - v;     // exclusive within block
    if (tx == 255) bsum[blockIdx.x] = s[255];  // block total
}

__global__ void scan2_kernel(int* __restrict__ bsum, int nb) {
    __shared__ int s[256];
    int tx = threadIdx.x;
    int v = (tx < nb) ? bsum[tx] : 0;
    s[tx] = v;
    __syncthreads();
    #pragma unroll
    for (int off = 1; off < 256; off <<= 1) {
        int t = (tx >= off) ? s[tx - off] : 0;
        __syncthreads();
        s[tx] += t;
        __syncthreads();
    }
    if (tx < nb) bsum[tx] = s[tx] - v;  // exclusive
}

__global__ void scan3_kernel(int* __restrict__ rowoff, const int* __restrict__ bsum) {
    int idx = blockIdx.x * 256 + threadIdx.x;
    if (idx < NN) rowoff[idx] += bsum[blockIdx.x];
    if (idx == 0) rowoff[NN] = NE;
}

__global__ void scatter_kernel(const int* __restrict__ ei, const int* __restrict__ rowoff,
                               int* __restrict__ cursor, int* __restrict__ csr_src) {
    int i = blockIdx.x * blockDim.x + threadIdx.x;
    int stride = gridDim.x * blockDim.x;
    for (int e = i; e < NE; e += stride) {
        int s = ei[e];
        int d = ei[NE + e];
        int pos = rowoff[d] + atomicAdd(&cursor[d], 1);
        csr_src[pos] = s;
    }
}

// ---------------------------------------------------------------- GEMM: Y = op(X) @ W
// X: nrows x 128, W: 128 x 128 (fully LDS-resident), Y: nrows x 128.
// 256 threads, 64-row tile, 4x8 micro-tile per thread.
template <bool RELU>
__global__ __launch_bounds__(256) void gemm_kernel(const float* __restrict__ X,
                                                   const float* __restrict__ W,
                                                   float* __restrict__ Y, int nrows) {
    __shared__ float Ws[128 * 128];  // 64 KB
    __shared__ float As[8][64];      // k-major (transposed) A tile, 2 KB
    int tid = threadIdx.x;
    {
        const float4* W4 = (const float4*)W;
        float4* S4 = (float4*)Ws;
        #pragma unroll
        for (int i = 0; i < 16; ++i) S4[tid + 256 * i] = W4[tid + 256 * i];
    }
    int row0 = blockIdx.x * 64;
    int tr = tid >> 4;  // 0..15 -> rows tr*4..tr*4+3
    int tc = tid & 15;  // 0..15 -> cols tc*8..tc*8+7
    int ar = tid >> 2;            // 0..63 : staged row
    int ak = (tid & 3) * 2;       // 0,2,4,6 : staged k pair
    const float* Xp = X + (row0 + ar) * DIM + ak;
    bool aok = (row0 + ar) < nrows;

    float acc[4][8];
    #pragma unroll
    for (int r = 0; r < 4; ++r)
        #pragma unroll
        for (int c = 0; c < 8; ++c) acc[r][c] = 0.0f;

    for (int k0 = 0; k0 < DIM; k0 += 8) {
        float2 av = make_float2(0.0f, 0.0f);
        if (aok) av = *(const float2*)(Xp + k0);
        if (RELU) { av.x = fmaxf(av.x, 0.0f); av.y = fmaxf(av.y, 0.0f); }
        __syncthreads();  // previous iter's As reads done
        As[ak][ar] = av.x;
        As[ak + 1][ar] = av.y;
        __syncthreads();  // As (and, iter 0, Ws) visible
        #pragma unroll
        for (int kk = 0; kk < 8; ++kk) {
            float4 a4 = *(const float4*)&As[kk][tr * 4];
            float4 b0 = *(const float4*)&Ws[(k0 + kk) * DIM + tc * 8];
            float4 b1 = *(const float4*)&Ws[(k0 + kk) * DIM + tc * 8 + 4];
            float a_[4] = {a4.x, a4.y, a4.z, a4.w};
            float b_[8] = {b0.x, b0.y, b0.z, b0.w, b1.x, b1.y, b1.z, b1.w};
            #pragma unroll
            for (int r = 0; r < 4; ++r)
                #pragma unroll
                for (int c = 0; c < 8; ++c) acc[r][c] = fmaf(a_[r], b_[c], acc[r][c]);
        }
    }
    #pragma unroll
    for (int r = 0; r < 4; ++r) {
        int row = row0 + tr * 4 + r;
        if (row < nrows) {
            float4 o0 = make_float4(acc[r][0], acc[r][1], acc[r][2], acc[r][3]);
            float4 o1 = make_float4(acc[r][4], acc[r][5], acc[r][6], acc[r][7]);
            *(float4*)&Y[row * DIM + tc * 8] = o0;
            *(float4*)&Y[row * DIM + tc * 8 + 4] = o1;
        }
    }
}

// ---------------------------------------------------------------- aggregation (CSR, no atomics)
// O[i] = dinv[i] * ( sum_{e in row i} dinv[src] * H[src] + dinv[i] * H[i] )
__global__ __launch_bounds__(128) void agg_kernel(const float* __restrict__ H,
                                                  float* __restrict__ O,
                                                  const int* __restrict__ rowoff,
                                                  const int* __restrict__ csr_src,
                                                  const float* __restrict__ dinv) {
    int i = blockIdx.x;
    int j = threadIdx.x;
    int s = rowoff[i];
    int e = rowoff[i + 1];
    float di = dinv[i];
    float acc = di * H[i * DIM + j];  // self-loop (second dinv[i] applied at end)
    for (int p = s; p < e; ++p) {
        int u = csr_src[p];
        acc = fmaf(dinv[u], H[u * DIM + j], acc);
    }
    O[i * DIM + j] = di * acc;
}

// ---------------------------------------------------------------- pooling (sorted batch, segmented)
#define POOL_CHUNK 512
__global__ __launch_bounds__(128) void pool_kernel(const float* __restrict__ H,
                                                   const int* __restrict__ batch,
                                                   float* __restrict__ gsum) {
    int j = threadIdx.x;
    int start = blockIdx.x * POOL_CHUNK;
    if (start >= NN) return;
    int end = min(start + POOL_CHUNK, NN);
    int cur = batch[start];
    float acc = 0.0f;
    for (int i = start; i < end; ++i) {
        int g = batch[i];
        if (g != cur) {
            atomicAdd(&gsum[cur * DIM + j], acc);
            acc = 0.0f;
            cur = g;
        }
        acc += H[i * DIM + j];
    }
    atomicAdd(&gsum[cur * DIM + j], acc);
}

// ---------------------------------------------------------------- final MLP
__global__ __launch_bounds__(128) void mlp_kernel(const float* __restrict__ gsum,
                                                  const int* __restrict__ gcnt,
                                                  const float* __restrict__ M0w,
                                                  const float* __restrict__ M0b,
                                                  const float* __restrict__ M1w,
                                                  const float* __restrict__ M1b,
                                                  float* __restrict__ out) {
    __shared__ float p[DIM];
    __shared__ float t[DIM];
    int g = blockIdx.x;
    int j = threadIdx.x;
    float cnt = (float)max(gcnt[g], 1);
    p[j] = gsum[g * DIM + j] / cnt;
    __syncthreads();
    float acc = M0b[j];
    #pragma unroll 8
    for (int k = 0; k < DIM; ++k) acc = fmaf(p[k], M0w[k * DIM + j], acc);
    t[j] = fmaxf(acc, 0.0f);
    __syncthreads();
    if (j < NOUT) {
        float o = M1b[j];
        #pragma unroll 8
        for (int k = 0; k < DIM; ++k) o = fmaf(t[k], M1w[k * NOUT + j], o);
        out[g * NOUT + j] = o;
    }
}

// ---------------------------------------------------------------- launcher
extern "C" void kernel_launch(void* const* d_in, const int* in_sizes, int n_in,
                              void* d_out, int out_size, void* d_ws, size_t ws_size,
                              hipStream_t stream) {
    const float* x   = (const float*)d_in[0];
    const float* W0  = (const float*)d_in[1];
    const float* W1  = (const float*)d_in[2];
    const float* W2  = (const float*)d_in[3];
    const float* M0w = (const float*)d_in[4];
    const float* M0b = (const float*)d_in[5];
    const float* M1w = (const float*)d_in[6];
    const float* M1b = (const float*)d_in[7];
    const int* ei    = (const int*)d_in[8];
    const int* batch = (const int*)d_in[9];
    float* out = (float*)d_out;

    char* ws = (char*)d_ws;
    size_t off = 0;
    auto take = [&](size_t bytes) -> void* {
        void* p = ws + off;
        off = (off + bytes + 255) & ~(size_t)255;
        return p;
    };
    float* hA = (float*)take((size_t)NN * DIM * 4);
    float* hB = (float*)take((size_t)NN * DIM * 4);
    size_t zero_off = off;
    int* deg_cnt = (int*)take((size_t)NN * 4);
    int* cursor  = (int*)take((size_t)NN * 4);
    float* gsum  = (float*)take((size_t)NG * DIM * 4);
    int* gcnt    = (int*)take((size_t)NG * 4);
    size_t zero_end = off;
    float* dinv  = (float*)take((size_t)NN * 4);
    int* rowoff  = (int*)take((size_t)(NN + 1) * 4);
    int* bsum    = (int*)take(256 * 4);
    int* csr_src = (int*)take((size_t)NE * 4);
    (void)ws_size; (void)in_sizes; (void)n_in; (void)out_size;

    hipMemsetAsync(ws + zero_off, 0, zero_end - zero_off, stream);

    const int NB = (NN + 255) / 256;  // 196 scan blocks
    count_kernel<<<512, 256, 0, stream>>>(ei, batch, deg_cnt, gcnt);
    dinv_kernel<<<NB, 256, 0, stream>>>(deg_cnt, dinv);
    scan1_kernel<<<NB, 256, 0, stream>>>(deg_cnt, rowoff, bsum);
    scan2_kernel<<<1, 256, 0, stream>>>(bsum, NB);
    scan3_kernel<<<NB, 256, 0, stream>>>(rowoff, bsum);
    scatter_kernel<<<512, 256, 0, stream>>>(ei, rowoff, cursor, csr_src);

    const int GB = (NN + 63) / 64;  // 782 gemm blocks
    gemm_kernel<false><<<GB, 256, 0, stream>>>(x, W0, hA, NN);
    agg_kernel<<<NN, 128, 0, stream>>>(hA, hB, rowoff, csr_src, dinv);
    gemm_kernel<true><<<GB, 256, 0, stream>>>(hB, W1, hA, NN);
    agg_kernel<<<NN, 128, 0, stream>>>(hA, hB, rowoff, csr_src, dinv);
    gemm_kernel<true><<<GB, 256, 0, stream>>>(hB, W2, hA, NN);
    agg_kernel<<<NN, 128, 0, stream>>>(hA, hB, rowoff, csr_src, dinv);

    pool_kernel<<<(NN + POOL_CHUNK - 1) / POOL_CHUNK, 128, 0, stream>>>(hB, batch, gsum);
    mlp_kernel<<<NG, 128, 0, stream>>>(gsum, gcnt, M0w, M0b, M1w, M1b, out);
}

// Round 2
// 574.454 us; speedup vs baseline: 1.6341x; 1.6341x over previous
//
#include <hip/hip_runtime.h>

#define NN 50000      // nodes
#define NE 800000     // edges
#define DIM 128       // feature dim (D == H)
#define NG 64         // graphs
#define NOUT 10       // output dim

#define NBKT 391      // coarse buckets: ceil(NN/128), dst>>7
#define HBLK 256      // histogram/scatter blocks
#define CHUNK ((NE + HBLK - 1) / HBLK)   // 3125 edges per block

// ---------------------------------------------------------------- pass A1: per-block bucket histogram
__global__ __launch_bounds__(256) void hist_kernel(const int* __restrict__ ei,
                                                   int* __restrict__ blkhist) {
    __shared__ int h[NBKT];
    int b = blockIdx.x;
    for (int i = threadIdx.x; i < NBKT; i += 256) h[i] = 0;
    __syncthreads();
    int lo = b * CHUNK, hi = min(lo + CHUNK, NE);
    for (int e = lo + threadIdx.x; e < hi; e += 256)
        atomicAdd(&h[ei[NE + e] >> 7], 1);  // LDS atomic
    __syncthreads();
    for (int i = threadIdx.x; i < NBKT; i += 256)
        blkhist[b * NBKT + i] = h[i];
}

// ---------------------------------------------------------------- pass A2a: bucket totals
__global__ __launch_bounds__(256) void bintot_kernel(const int* __restrict__ blkhist,
                                                     int* __restrict__ bintot) {
    __shared__ int s[256];
    int bin = blockIdx.x;
    int t = threadIdx.x;
    s[t] = blkhist[t * NBKT + bin];
    __syncthreads();
    #pragma unroll
    for (int off = 128; off > 0; off >>= 1) {
        if (t < off) s[t] += s[t + off];
        __syncthreads();
    }
    if (t == 0) bintot[bin] = s[0];
}

// ---------------------------------------------------------------- pass A2b: scan bucket totals -> bucket_base
__global__ __launch_bounds__(512) void base_scan_kernel(const int* __restrict__ bintot,
                                                        int* __restrict__ bucket_base) {
    __shared__ int s[512];
    int t = threadIdx.x;
    int v = (t < NBKT) ? bintot[t] : 0;
    s[t] = v;
    __syncthreads();
    #pragma unroll
    for (int off = 1; off < 512; off <<= 1) {
        int tv = (t >= off) ? s[t - off] : 0;
        __syncthreads();
        s[t] += tv;
        __syncthreads();
    }
    if (t <= NBKT) bucket_base[t] = s[t] - v;  // exclusive; t==NBKT -> NE
}

// ---------------------------------------------------------------- pass A2c: per-(bucket,block) absolute offsets
__global__ __launch_bounds__(256) void binoff_kernel(int* __restrict__ blkhist,
                                                     const int* __restrict__ bucket_base) {
    __shared__ int s[256];
    int bin = blockIdx.x;
    int t = threadIdx.x;
    int v = blkhist[t * NBKT + bin];
    s[t] = v;
    __syncthreads();
    #pragma unroll
    for (int off = 1; off < 256; off <<= 1) {
        int tv = (t >= off) ? s[t - off] : 0;
        __syncthreads();
        s[t] += tv;
        __syncthreads();
    }
    blkhist[t * NBKT + bin] = bucket_base[bin] + s[t] - v;  // absolute start
}

// ---------------------------------------------------------------- pass A3: scatter edges into buckets (packed)
__global__ __launch_bounds__(256) void bucket_scatter(const int* __restrict__ ei,
                                                      const int* __restrict__ blkhist,
                                                      unsigned* __restrict__ ebuf) {
    __shared__ int cur[NBKT];
    int b = blockIdx.x;
    for (int i = threadIdx.x; i < NBKT; i += 256) cur[i] = blkhist[b * NBKT + i];
    __syncthreads();
    int lo = b * CHUNK, hi = min(lo + CHUNK, NE);
    for (int e = lo + threadIdx.x; e < hi; e += 256) {
        int s = ei[e];
        int d = ei[NE + e];
        int pos = atomicAdd(&cur[d >> 7], 1);  // LDS atomic; block owns disjoint ranges
        ebuf[pos] = ((unsigned)(d & 127) << 16) | (unsigned)s;  // src < 2^16
    }
}

// ---------------------------------------------------------------- pass B: per-bucket CSR build (no global atomics)
__global__ __launch_bounds__(128) void build_csr(const unsigned* __restrict__ ebuf,
                                                 const int* __restrict__ bucket_base,
                                                 int* __restrict__ rowoff,
                                                 int* __restrict__ csr_src,
                                                 float* __restrict__ dinv) {
    __shared__ int deg[128];
    __shared__ int loff[128];
    int g = blockIdx.x;
    int lo = bucket_base[g], hi = bucket_base[g + 1];
    int t = threadIdx.x;
    deg[t] = 0;
    __syncthreads();
    for (int p = lo + t; p < hi; p += 128)
        atomicAdd(&deg[ebuf[p] >> 16], 1);
    __syncthreads();
    int v = deg[t];
    loff[t] = v;
    __syncthreads();
    #pragma unroll
    for (int off = 1; off < 128; off <<= 1) {
        int tv = (t >= off) ? loff[t - off] : 0;
        __syncthreads();
        loff[t] += tv;
        __syncthreads();
    }
    int excl = loff[t] - v;
    int node = g * 128 + t;
    if (node < NN) {
        rowoff[node] = lo + excl;
        dinv[node] = 1.0f / sqrtf((float)v + 1.0f);
    }
    if (node == 0) rowoff[NN] = NE;
    deg[t] = lo + excl;  // reuse as cursor
    __syncthreads();
    for (int p = lo + t; p < hi; p += 128) {
        unsigned pk = ebuf[p];
        int pos = atomicAdd(&deg[pk >> 16], 1);
        csr_src[pos] = (int)(pk & 0xFFFFu);
    }
}

// ---------------------------------------------------------------- graph boundaries (batch is sorted)
__global__ __launch_bounds__(128) void bounds_kernel(const int* __restrict__ batch,
                                                     int* __restrict__ first) {
    int g = threadIdx.x;
    if (g <= NG) {
        int lo = 0, hi = NN;
        while (lo < hi) {
            int mid = (lo + hi) >> 1;
            if (batch[mid] < g) lo = mid + 1; else hi = mid;
        }
        first[g] = lo;  // lower_bound(batch, g)
    }
}

// ---------------------------------------------------------------- GEMM: Y = op(X) @ W
template <bool RELU>
__global__ __launch_bounds__(256) void gemm_kernel(const float* __restrict__ X,
                                                   const float* __restrict__ W,
                                                   float* __restrict__ Y, int nrows) {
    __shared__ float Ws[128 * 128];  // 64 KB
    __shared__ float As[8][64];      // k-major A tile
    int tid = threadIdx.x;
    {
        const float4* W4 = (const float4*)W;
        float4* S4 = (float4*)Ws;
        #pragma unroll
        for (int i = 0; i < 16; ++i) S4[tid + 256 * i] = W4[tid + 256 * i];
    }
    int row0 = blockIdx.x * 64;
    int tr = tid >> 4;
    int tc = tid & 15;
    int ar = tid >> 2;
    int ak = (tid & 3) * 2;
    const float* Xp = X + (row0 + ar) * DIM + ak;
    bool aok = (row0 + ar) < nrows;

    float acc[4][8];
    #pragma unroll
    for (int r = 0; r < 4; ++r)
        #pragma unroll
        for (int c = 0; c < 8; ++c) acc[r][c] = 0.0f;

    for (int k0 = 0; k0 < DIM; k0 += 8) {
        float2 av = make_float2(0.0f, 0.0f);
        if (aok) av = *(const float2*)(Xp + k0);
        if (RELU) { av.x = fmaxf(av.x, 0.0f); av.y = fmaxf(av.y, 0.0f); }
        __syncthreads();
        As[ak][ar] = av.x;
        As[ak + 1][ar] = av.y;
        __syncthreads();
        #pragma unroll
        for (int kk = 0; kk < 8; ++kk) {
            float4 a4 = *(const float4*)&As[kk][tr * 4];
            float4 b0 = *(const float4*)&Ws[(k0 + kk) * DIM + tc * 8];
            float4 b1 = *(const float4*)&Ws[(k0 + kk) * DIM + tc * 8 + 4];
            float a_[4] = {a4.x, a4.y, a4.z, a4.w};
            float b_[8] = {b0.x, b0.y, b0.z, b0.w, b1.x, b1.y, b1.z, b1.w};
            #pragma unroll
            for (int r = 0; r < 4; ++r)
                #pragma unroll
                for (int c = 0; c < 8; ++c) acc[r][c] = fmaf(a_[r], b_[c], acc[r][c]);
        }
    }
    #pragma unroll
    for (int r = 0; r < 4; ++r) {
        int row = row0 + tr * 4 + r;
        if (row < nrows) {
            float4 o0 = make_float4(acc[r][0], acc[r][1], acc[r][2], acc[r][3]);
            float4 o1 = make_float4(acc[r][4], acc[r][5], acc[r][6], acc[r][7]);
            *(float4*)&Y[row * DIM + tc * 8] = o0;
            *(float4*)&Y[row * DIM + tc * 8 + 4] = o1;
        }
    }
}

// ---------------------------------------------------------------- aggregation (CSR, no atomics)
__global__ __launch_bounds__(128) void agg_kernel(const float* __restrict__ H,
                                                  float* __restrict__ O,
                                                  const int* __restrict__ rowoff,
                                                  const int* __restrict__ csr_src,
                                                  const float* __restrict__ dinv) {
    int i = blockIdx.x;
    int j = threadIdx.x;
    int s = rowoff[i];
    int e = rowoff[i + 1];
    float di = dinv[i];
    float acc = di * H[i * DIM + j];
    for (int p = s; p < e; ++p) {
        int u = csr_src[p];
        acc = fmaf(dinv[u], H[u * DIM + j], acc);
    }
    O[i * DIM + j] = di * acc;
}

// ---------------------------------------------------------------- pooling: one block per graph (no atomics)
__global__ __launch_bounds__(128) void pool_kernel(const float* __restrict__ H,
                                                   const int* __restrict__ first,
                                                   float* __restrict__ pooled) {
    int g = blockIdx.x;
    int j = threadIdx.x;
    int s = first[g], e = first[g + 1];
    float acc = 0.0f;
    #pragma unroll 4
    for (int i = s; i < e; ++i) acc += H[i * DIM + j];
    float cnt = (float)max(e - s, 1);
    pooled[g * DIM + j] = acc / cnt;
}

// ---------------------------------------------------------------- final MLP
__global__ __launch_bounds__(128) void mlp_kernel(const float* __restrict__ pooled,
                                                  const float* __restrict__ M0w,
                                                  const float* __restrict__ M0b,
                                                  const float* __restrict__ M1w,
                                                  const float* __restrict__ M1b,
                                                  float* __restrict__ out) {
    __shared__ float p[DIM];
    __shared__ float t[DIM];
    int g = blockIdx.x;
    int j = threadIdx.x;
    p[j] = pooled[g * DIM + j];
    __syncthreads();
    float acc = M0b[j];
    #pragma unroll 8
    for (int k = 0; k < DIM; ++k) acc = fmaf(p[k], M0w[k * DIM + j], acc);
    t[j] = fmaxf(acc, 0.0f);
    __syncthreads();
    if (j < NOUT) {
        float o = M1b[j];
        #pragma unroll 8
        for (int k = 0; k < DIM; ++k) o = fmaf(t[k], M1w[k * NOUT + j], o);
        out[g * NOUT + j] = o;
    }
}

// ---------------------------------------------------------------- launcher
extern "C" void kernel_launch(void* const* d_in, const int* in_sizes, int n_in,
                              void* d_out, int out_size, void* d_ws, size_t ws_size,
                              hipStream_t stream) {
    const float* x   = (const float*)d_in[0];
    const float* W0  = (const float*)d_in[1];
    const float* W1  = (const float*)d_in[2];
    const float* W2  = (const float*)d_in[3];
    const float* M0w = (const float*)d_in[4];
    const float* M0b = (const float*)d_in[5];
    const float* M1w = (const float*)d_in[6];
    const float* M1b = (const float*)d_in[7];
    const int* ei    = (const int*)d_in[8];
    const int* batch = (const int*)d_in[9];
    float* out = (float*)d_out;

    char* ws = (char*)d_ws;
    size_t off = 0;
    auto take = [&](size_t bytes) -> void* {
        void* p = ws + off;
        off = (off + bytes + 255) & ~(size_t)255;
        return p;
    };
    float* hA    = (float*)take((size_t)NN * DIM * 4);
    float* hB    = (float*)take((size_t)NN * DIM * 4);
    unsigned* ebuf = (unsigned*)take((size_t)NE * 4);
    int* csr_src = (int*)take((size_t)NE * 4);
    int* blkhist = (int*)take((size_t)HBLK * NBKT * 4);
    int* bintot  = (int*)take((size_t)NBKT * 4);
    int* bucket_base = (int*)take((size_t)(NBKT + 1) * 4);
    int* rowoff  = (int*)take((size_t)(NN + 1) * 4);
    float* dinv  = (float*)take((size_t)NN * 4);
    int* first   = (int*)take((size_t)(NG + 1) * 4);
    float* pooled = (float*)take((size_t)NG * DIM * 4);
    (void)ws_size; (void)in_sizes; (void)n_in; (void)out_size;

    // ---- CSR build: bucket counting-sort, zero global atomics
    hist_kernel<<<HBLK, 256, 0, stream>>>(ei, blkhist);
    bintot_kernel<<<NBKT, 256, 0, stream>>>(blkhist, bintot);
    base_scan_kernel<<<1, 512, 0, stream>>>(bintot, bucket_base);
    binoff_kernel<<<NBKT, 256, 0, stream>>>(blkhist, bucket_base);
    bucket_scatter<<<HBLK, 256, 0, stream>>>(ei, blkhist, ebuf);
    build_csr<<<NBKT, 128, 0, stream>>>(ebuf, bucket_base, rowoff, csr_src, dinv);
    bounds_kernel<<<1, 128, 0, stream>>>(batch, first);

    // ---- 3x (GEMM -> aggregate)
    const int GB = (NN + 63) / 64;
    gemm_kernel<false><<<GB, 256, 0, stream>>>(x, W0, hA, NN);
    agg_kernel<<<NN, 128, 0, stream>>>(hA, hB, rowoff, csr_src, dinv);
    gemm_kernel<true><<<GB, 256, 0, stream>>>(hB, W1, hA, NN);
    agg_kernel<<<NN, 128, 0, stream>>>(hA, hB, rowoff, csr_src, dinv);
    gemm_kernel<true><<<GB, 256, 0, stream>>>(hB, W2, hA, NN);
    agg_kernel<<<NN, 128, 0, stream>>>(hA, hB, rowoff, csr_src, dinv);

    // ---- pool + MLP
    pool_kernel<<<NG, 128, 0, stream>>>(hB, first, pooled);
    mlp_kernel<<<NG, 128, 0, stream>>>(pooled, M0w, M0b, M1w, M1b, out);
}

// Round 3
// 526.617 us; speedup vs baseline: 1.7825x; 1.0908x over previous
//
#include <hip/hip_runtime.h>

#define NN 50000      // nodes
#define NE 800000     // edges
#define DIM 128       // feature dim (D == H)
#define NG 64         // graphs
#define NOUT 10       // output dim

#define NBKT 391      // coarse buckets: ceil(NN/128), dst>>7
#define HBLK 256      // histogram/scatter blocks
#define CHUNK ((NE + HBLK - 1) / HBLK)   // 3125 edges per block

typedef __attribute__((ext_vector_type(8))) short short8;
typedef __attribute__((ext_vector_type(4))) float float4v;

// ---------------------------------------------------------------- pass A1: per-block bucket histogram
__global__ __launch_bounds__(256) void hist_kernel(const int* __restrict__ ei,
                                                   int* __restrict__ blkhist) {
    __shared__ int h[NBKT];
    int b = blockIdx.x;
    for (int i = threadIdx.x; i < NBKT; i += 256) h[i] = 0;
    __syncthreads();
    int lo = b * CHUNK, hi = min(lo + CHUNK, NE);
    for (int e = lo + threadIdx.x; e < hi; e += 256)
        atomicAdd(&h[ei[NE + e] >> 7], 1);  // LDS atomic
    __syncthreads();
    for (int i = threadIdx.x; i < NBKT; i += 256)
        blkhist[b * NBKT + i] = h[i];
}

// ---------------------------------------------------------------- pass A2a: bucket totals
__global__ __launch_bounds__(256) void bintot_kernel(const int* __restrict__ blkhist,
                                                     int* __restrict__ bintot) {
    __shared__ int s[256];
    int bin = blockIdx.x;
    int t = threadIdx.x;
    s[t] = blkhist[t * NBKT + bin];
    __syncthreads();
    #pragma unroll
    for (int off = 128; off > 0; off >>= 1) {
        if (t < off) s[t] += s[t + off];
        __syncthreads();
    }
    if (t == 0) bintot[bin] = s[0];
}

// ---------------------------------------------------------------- pass A2b: scan bucket totals -> bucket_base
__global__ __launch_bounds__(512) void base_scan_kernel(const int* __restrict__ bintot,
                                                        int* __restrict__ bucket_base) {
    __shared__ int s[512];
    int t = threadIdx.x;
    int v = (t < NBKT) ? bintot[t] : 0;
    s[t] = v;
    __syncthreads();
    #pragma unroll
    for (int off = 1; off < 512; off <<= 1) {
        int tv = (t >= off) ? s[t - off] : 0;
        __syncthreads();
        s[t] += tv;
        __syncthreads();
    }
    if (t <= NBKT) bucket_base[t] = s[t] - v;  // exclusive; t==NBKT -> NE
}

// ---------------------------------------------------------------- pass A2c: per-(bucket,block) absolute offsets
__global__ __launch_bounds__(256) void binoff_kernel(int* __restrict__ blkhist,
                                                     const int* __restrict__ bucket_base) {
    __shared__ int s[256];
    int bin = blockIdx.x;
    int t = threadIdx.x;
    int v = blkhist[t * NBKT + bin];
    s[t] = v;
    __syncthreads();
    #pragma unroll
    for (int off = 1; off < 256; off <<= 1) {
        int tv = (t >= off) ? s[t - off] : 0;
        __syncthreads();
        s[t] += tv;
        __syncthreads();
    }
    blkhist[t * NBKT + bin] = bucket_base[bin] + s[t] - v;  // absolute start
}

// ---------------------------------------------------------------- pass A3: scatter edges into buckets (packed)
__global__ __launch_bounds__(256) void bucket_scatter(const int* __restrict__ ei,
                                                      const int* __restrict__ blkhist,
                                                      unsigned* __restrict__ ebuf) {
    __shared__ int cur[NBKT];
    int b = blockIdx.x;
    for (int i = threadIdx.x; i < NBKT; i += 256) cur[i] = blkhist[b * NBKT + i];
    __syncthreads();
    int lo = b * CHUNK, hi = min(lo + CHUNK, NE);
    for (int e = lo + threadIdx.x; e < hi; e += 256) {
        int s = ei[e];
        int d = ei[NE + e];
        int pos = atomicAdd(&cur[d >> 7], 1);  // LDS atomic; block owns disjoint ranges
        ebuf[pos] = ((unsigned)(d & 127) << 16) | (unsigned)s;  // src < 2^16
    }
}

// ---------------------------------------------------------------- pass B: per-bucket CSR build
__global__ __launch_bounds__(128) void build_csr(const unsigned* __restrict__ ebuf,
                                                 const int* __restrict__ bucket_base,
                                                 int* __restrict__ rowoff,
                                                 int* __restrict__ csr_src,
                                                 float* __restrict__ dinv) {
    __shared__ int deg[128];
    __shared__ int loff[128];
    int g = blockIdx.x;
    int lo = bucket_base[g], hi = bucket_base[g + 1];
    int t = threadIdx.x;
    deg[t] = 0;
    __syncthreads();
    for (int p = lo + t; p < hi; p += 128)
        atomicAdd(&deg[ebuf[p] >> 16], 1);
    __syncthreads();
    int v = deg[t];
    loff[t] = v;
    __syncthreads();
    #pragma unroll
    for (int off = 1; off < 128; off <<= 1) {
        int tv = (t >= off) ? loff[t - off] : 0;
        __syncthreads();
        loff[t] += tv;
        __syncthreads();
    }
    int excl = loff[t] - v;
    int node = g * 128 + t;
    if (node < NN) {
        rowoff[node] = lo + excl;
        dinv[node] = 1.0f / sqrtf((float)v + 1.0f);
    }
    if (node == 0) rowoff[NN] = NE;
    deg[t] = lo + excl;  // reuse as cursor
    __syncthreads();
    for (int p = lo + t; p < hi; p += 128) {
        unsigned pk = ebuf[p];
        int pos = atomicAdd(&deg[pk >> 16], 1);
        csr_src[pos] = (int)(pk & 0xFFFFu);
    }
}

// ---------------------------------------------------------------- graph boundaries (batch is sorted)
__global__ __launch_bounds__(128) void bounds_kernel(const int* __restrict__ batch,
                                                     int* __restrict__ first) {
    int g = threadIdx.x;
    if (g <= NG) {
        int lo = 0, hi = NN;
        while (lo < hi) {
            int mid = (lo + hi) >> 1;
            if (batch[mid] < g) lo = mid + 1; else hi = mid;
        }
        first[g] = lo;  // lower_bound(batch, g)
    }
}

// ---------------------------------------------------------------- W prep: f32 [k][n] -> bf16 hi/lo transposed [n][k]
__global__ __launch_bounds__(256) void wprep_kernel(const float* __restrict__ W0,
                                                    const float* __restrict__ W1,
                                                    const float* __restrict__ W2,
                                                    short* __restrict__ out) {
    const float* W = (blockIdx.x == 0) ? W0 : (blockIdx.x == 1) ? W1 : W2;
    short* Wh = out + blockIdx.x * 2 * DIM * DIM;
    short* Wl = Wh + DIM * DIM;
    for (int idx = threadIdx.x; idx < DIM * DIM; idx += 256) {
        int k = idx >> 7, n = idx & 127;
        float v = W[idx];
        unsigned u = __float_as_uint(v);
        unsigned hb = (u + 0x7FFFu + ((u >> 16) & 1u)) & 0xFFFF0000u;  // RNE bf16
        float res = v - __uint_as_float(hb);
        unsigned u2 = __float_as_uint(res);
        unsigned lb = (u2 + 0x7FFFu + ((u2 >> 16) & 1u)) >> 16;
        Wh[n * DIM + k] = (short)(hb >> 16);
        Wl[n * DIM + k] = (short)lb;
    }
}

// ---------------------------------------------------------------- GEMM: Y = op(X) @ W via split-bf16 MFMA
// 3-term split: x*w = xh*wh + xl*wh + xh*wl  (al*bl dropped, ~2^-18 rel err)
#define WPAD 136  // LDS row stride in shorts (+8 pad: 4*lm%32 spread, b128-aligned)
template <bool RELU>
__global__ __launch_bounds__(256) void gemm_mfma(const float* __restrict__ X,
                                                 const short* __restrict__ Wsp,
                                                 float* __restrict__ Y, int nrows) {
    __shared__ short Wh[DIM * WPAD];
    __shared__ short Wl[DIM * WPAD];
    int tid = threadIdx.x;
    {
        const short8* gh = (const short8*)Wsp;                // [n][k], 2048 short8
        const short8* gl = (const short8*)(Wsp + DIM * DIM);
        #pragma unroll
        for (int i = 0; i < 8; ++i) {
            int e = tid + 256 * i;        // short8 index
            int n = e >> 4;
            int k = (e & 15) * 8;
            *(short8*)&Wh[n * WPAD + k] = gh[e];
            *(short8*)&Wl[n * WPAD + k] = gl[e];
        }
    }
    int wave = tid >> 6;
    int lane = tid & 63;
    int lm = lane & 15;   // A row within tile / B col within tile / D col
    int lq = lane >> 4;   // k-octet selector / D row-quad
    int row0 = blockIdx.x * 64 + wave * 16;
    int rr = min(row0 + lm, nrows - 1);
    const float* Xp = X + (size_t)rr * DIM + lq * 8;

    float4v acc[8];
    #pragma unroll
    for (int i = 0; i < 8; ++i) acc[i] = (float4v){0.f, 0.f, 0.f, 0.f};

    __syncthreads();
    #pragma unroll
    for (int kk = 0; kk < 4; ++kk) {
        float4 xa = *(const float4*)(Xp + kk * 32);
        float4 xb = *(const float4*)(Xp + kk * 32 + 4);
        float xv[8] = {xa.x, xa.y, xa.z, xa.w, xb.x, xb.y, xb.z, xb.w};
        short8 ah, al;
        #pragma unroll
        for (int j = 0; j < 8; ++j) {
            float v = xv[j];
            if (RELU) v = fmaxf(v, 0.0f);
            unsigned u = __float_as_uint(v);
            unsigned hb = (u + 0x7FFFu + ((u >> 16) & 1u)) & 0xFFFF0000u;
            float res = v - __uint_as_float(hb);
            unsigned u2 = __float_as_uint(res);
            unsigned lb = (u2 + 0x7FFFu + ((u2 >> 16) & 1u)) >> 16;
            ah[j] = (short)(hb >> 16);
            al[j] = (short)lb;
        }
        #pragma unroll
        for (int n0 = 0; n0 < 8; ++n0) {
            short8 bh = *(const short8*)&Wh[(n0 * 16 + lm) * WPAD + kk * 32 + lq * 8];
            short8 bl = *(const short8*)&Wl[(n0 * 16 + lm) * WPAD + kk * 32 + lq * 8];
            acc[n0] = __builtin_amdgcn_mfma_f32_16x16x32_bf16(ah, bh, acc[n0], 0, 0, 0);
            acc[n0] = __builtin_amdgcn_mfma_f32_16x16x32_bf16(al, bh, acc[n0], 0, 0, 0);
            acc[n0] = __builtin_amdgcn_mfma_f32_16x16x32_bf16(ah, bl, acc[n0], 0, 0, 0);
        }
    }
    // D layout: col = lane&15, row = (lane>>4)*4 + reg  [verified m89/m91]
    #pragma unroll
    for (int n0 = 0; n0 < 8; ++n0) {
        #pragma unroll
        for (int rg = 0; rg < 4; ++rg) {
            int row = row0 + lq * 4 + rg;
            if (row < nrows) Y[(size_t)row * DIM + n0 * 16 + lm] = acc[n0][rg];
        }
    }
}

// ---------------------------------------------------------------- aggregation (CSR, 4 edge-groups x float4, MLP-optimized)
__global__ __launch_bounds__(128) void agg_kernel(const float* __restrict__ H,
                                                  float* __restrict__ O,
                                                  const int* __restrict__ rowoff,
                                                  const int* __restrict__ csr_src,
                                                  const float* __restrict__ dinv) {
    __shared__ float part[4][DIM];
    int i = blockIdx.x;
    int tid = threadIdx.x;
    int grp = tid >> 5, ln = tid & 31;
    int s = rowoff[i], e = rowoff[i + 1];
    const float* Hc = H + ln * 4;

    float4 a1 = make_float4(0.f, 0.f, 0.f, 0.f);
    float4 a2 = make_float4(0.f, 0.f, 0.f, 0.f);
    int p = s + grp;
    for (; p + 4 < e; p += 8) {
        int u1 = csr_src[p];
        int u2 = csr_src[p + 4];
        float d1 = dinv[u1];
        float d2 = dinv[u2];
        float4 h1 = *(const float4*)(Hc + (size_t)u1 * DIM);
        float4 h2 = *(const float4*)(Hc + (size_t)u2 * DIM);
        a1.x = fmaf(d1, h1.x, a1.x); a1.y = fmaf(d1, h1.y, a1.y);
        a1.z = fmaf(d1, h1.z, a1.z); a1.w = fmaf(d1, h1.w, a1.w);
        a2.x = fmaf(d2, h2.x, a2.x); a2.y = fmaf(d2, h2.y, a2.y);
        a2.z = fmaf(d2, h2.z, a2.z); a2.w = fmaf(d2, h2.w, a2.w);
    }
    if (p < e) {
        int u = csr_src[p];
        float d = dinv[u];
        float4 h = *(const float4*)(Hc + (size_t)u * DIM);
        a1.x = fmaf(d, h.x, a1.x); a1.y = fmaf(d, h.y, a1.y);
        a1.z = fmaf(d, h.z, a1.z); a1.w = fmaf(d, h.w, a1.w);
    }
    a1.x += a2.x; a1.y += a2.y; a1.z += a2.z; a1.w += a2.w;
    *(float4*)&part[grp][ln * 4] = a1;
    __syncthreads();
    // thread tid finalizes column tid
    float di = dinv[i];
    float tot = part[0][tid] + part[1][tid] + part[2][tid] + part[3][tid];
    tot = fmaf(di, H[(size_t)i * DIM + tid], tot);  // self-loop
    O[(size_t)i * DIM + tid] = di * tot;
}

// ---------------------------------------------------------------- pooling (sorted batch, segmented + atomics)
#define POOL_CHUNK 512
__global__ __launch_bounds__(128) void pool_kernel(const float* __restrict__ H,
                                                   const int* __restrict__ batch,
                                                   float* __restrict__ gsum) {
    int j = threadIdx.x;
    int start = blockIdx.x * POOL_CHUNK;
    if (start >= NN) return;
    int end = min(start + POOL_CHUNK, NN);
    int cur = batch[start];
    float acc = 0.0f;
    for (int i = start; i < end; ++i) {
        int g = batch[i];
        if (g != cur) {
            atomicAdd(&gsum[cur * DIM + j], acc);
            acc = 0.0f;
            cur = g;
        }
        acc += H[(size_t)i * DIM + j];
    }
    atomicAdd(&gsum[cur * DIM + j], acc);
}

// ---------------------------------------------------------------- final MLP
__global__ __launch_bounds__(128) void mlp_kernel(const float* __restrict__ gsum,
                                                  const int* __restrict__ first,
                                                  const float* __restrict__ M0w,
                                                  const float* __restrict__ M0b,
                                                  const float* __restrict__ M1w,
                                                  const float* __restrict__ M1b,
                                                  float* __restrict__ out) {
    __shared__ float p[DIM];
    __shared__ float t[DIM];
    int g = blockIdx.x;
    int j = threadIdx.x;
    float cnt = (float)max(first[g + 1] - first[g], 1);
    p[j] = gsum[g * DIM + j] / cnt;
    __syncthreads();
    float acc = M0b[j];
    #pragma unroll 8
    for (int k = 0; k < DIM; ++k) acc = fmaf(p[k], M0w[k * DIM + j], acc);
    t[j] = fmaxf(acc, 0.0f);
    __syncthreads();
    if (j < NOUT) {
        float o = M1b[j];
        #pragma unroll 8
        for (int k = 0; k < DIM; ++k) o = fmaf(t[k], M1w[k * NOUT + j], o);
        out[g * NOUT + j] = o;
    }
}

// ---------------------------------------------------------------- launcher
extern "C" void kernel_launch(void* const* d_in, const int* in_sizes, int n_in,
                              void* d_out, int out_size, void* d_ws, size_t ws_size,
                              hipStream_t stream) {
    const float* x   = (const float*)d_in[0];
    const float* W0  = (const float*)d_in[1];
    const float* W1  = (const float*)d_in[2];
    const float* W2  = (const float*)d_in[3];
    const float* M0w = (const float*)d_in[4];
    const float* M0b = (const float*)d_in[5];
    const float* M1w = (const float*)d_in[6];
    const float* M1b = (const float*)d_in[7];
    const int* ei    = (const int*)d_in[8];
    const int* batch = (const int*)d_in[9];
    float* out = (float*)d_out;

    char* ws = (char*)d_ws;
    size_t off = 0;
    auto take = [&](size_t bytes) -> void* {
        void* p = ws + off;
        off = (off + bytes + 255) & ~(size_t)255;
        return p;
    };
    float* hA    = (float*)take((size_t)NN * DIM * 4);
    float* hB    = (float*)take((size_t)NN * DIM * 4);
    unsigned* ebuf = (unsigned*)take((size_t)NE * 4);
    int* csr_src = (int*)take((size_t)NE * 4);
    int* blkhist = (int*)take((size_t)HBLK * NBKT * 4);
    int* bintot  = (int*)take((size_t)NBKT * 4);
    int* bucket_base = (int*)take((size_t)(NBKT + 1) * 4);
    int* rowoff  = (int*)take((size_t)(NN + 1) * 4);
    float* dinv  = (float*)take((size_t)NN * 4);
    int* first   = (int*)take((size_t)(NG + 1) * 4);
    float* gsum  = (float*)take((size_t)NG * DIM * 4);
    short* wsp   = (short*)take((size_t)3 * 2 * DIM * DIM * 2);
    (void)ws_size; (void)in_sizes; (void)n_in; (void)out_size;

    // ---- weight split (bf16 hi/lo, transposed) + CSR build
    wprep_kernel<<<3, 256, 0, stream>>>(W0, W1, W2, wsp);
    hist_kernel<<<HBLK, 256, 0, stream>>>(ei, blkhist);
    bintot_kernel<<<NBKT, 256, 0, stream>>>(blkhist, bintot);
    base_scan_kernel<<<1, 512, 0, stream>>>(bintot, bucket_base);
    binoff_kernel<<<NBKT, 256, 0, stream>>>(blkhist, bucket_base);
    bucket_scatter<<<HBLK, 256, 0, stream>>>(ei, blkhist, ebuf);
    build_csr<<<NBKT, 128, 0, stream>>>(ebuf, bucket_base, rowoff, csr_src, dinv);
    bounds_kernel<<<1, 128, 0, stream>>>(batch, first);
    hipMemsetAsync(gsum, 0, (size_t)NG * DIM * 4, stream);

    // ---- 3x (GEMM -> aggregate)
    const int GB = (NN + 63) / 64;
    gemm_mfma<false><<<GB, 256, 0, stream>>>(x, wsp, hA, NN);
    agg_kernel<<<NN, 128, 0, stream>>>(hA, hB, rowoff, csr_src, dinv);
    gemm_mfma<true><<<GB, 256, 0, stream>>>(hB, wsp + 2 * DIM * DIM, hA, NN);
    agg_kernel<<<NN, 128, 0, stream>>>(hA, hB, rowoff, csr_src, dinv);
    gemm_mfma<true><<<GB, 256, 0, stream>>>(hB, wsp + 4 * DIM * DIM, hA, NN);
    agg_kernel<<<NN, 128, 0, stream>>>(hA, hB, rowoff, csr_src, dinv);

    // ---- pool + MLP
    pool_kernel<<<(NN + POOL_CHUNK - 1) / POOL_CHUNK, 128, 0, stream>>>(hB, batch, gsum);
    mlp_kernel<<<NG, 128, 0, stream>>>(gsum, first, M0w, M0b, M1w, M1b, out);
}

// Round 4
// 397.338 us; speedup vs baseline: 2.3625x; 1.3254x over previous
//
#include <hip/hip_runtime.h>

#define NN 50000      // nodes
#define NE 800000     // edges
#define DIM 128       // feature dim (D == H)
#define NG 64         // graphs
#define NOUT 10       // output dim

#define NBKT 391      // coarse buckets: ceil(NN/128), dst>>7
#define HBLK 256      // histogram/scatter blocks
#define CHUNK ((NE + HBLK - 1) / HBLK)   // 3125 edges per block
#define PSLICE 8      // pooling slices per graph

typedef __attribute__((ext_vector_type(8))) short short8;
typedef __attribute__((ext_vector_type(4))) float float4v;

// ---------------------------------------------------------------- pass A1: per-block bucket histogram
__global__ __launch_bounds__(256) void hist_kernel(const int* __restrict__ ei,
                                                   int* __restrict__ blkhist) {
    __shared__ int h[NBKT];
    int b = blockIdx.x;
    for (int i = threadIdx.x; i < NBKT; i += 256) h[i] = 0;
    __syncthreads();
    int lo = b * CHUNK, hi = min(lo + CHUNK, NE);
    for (int e = lo + threadIdx.x; e < hi; e += 256)
        atomicAdd(&h[ei[NE + e] >> 7], 1);  // LDS atomic
    __syncthreads();
    for (int i = threadIdx.x; i < NBKT; i += 256)
        blkhist[b * NBKT + i] = h[i];
}

// ---------------------------------------------------------------- pass A2a: bucket totals
__global__ __launch_bounds__(256) void bintot_kernel(const int* __restrict__ blkhist,
                                                     int* __restrict__ bintot) {
    __shared__ int s[256];
    int bin = blockIdx.x;
    int t = threadIdx.x;
    s[t] = blkhist[t * NBKT + bin];
    __syncthreads();
    #pragma unroll
    for (int off = 128; off > 0; off >>= 1) {
        if (t < off) s[t] += s[t + off];
        __syncthreads();
    }
    if (t == 0) bintot[bin] = s[0];
}

// ---------------------------------------------------------------- pass A2b: scan bucket totals -> bucket_base
__global__ __launch_bounds__(512) void base_scan_kernel(const int* __restrict__ bintot,
                                                        int* __restrict__ bucket_base) {
    __shared__ int s[512];
    int t = threadIdx.x;
    int v = (t < NBKT) ? bintot[t] : 0;
    s[t] = v;
    __syncthreads();
    #pragma unroll
    for (int off = 1; off < 512; off <<= 1) {
        int tv = (t >= off) ? s[t - off] : 0;
        __syncthreads();
        s[t] += tv;
        __syncthreads();
    }
    if (t <= NBKT) bucket_base[t] = s[t] - v;  // exclusive; t==NBKT -> NE
}

// ---------------------------------------------------------------- pass A2c: per-(bucket,block) absolute offsets
__global__ __launch_bounds__(256) void binoff_kernel(int* __restrict__ blkhist,
                                                     const int* __restrict__ bucket_base) {
    __shared__ int s[256];
    int bin = blockIdx.x;
    int t = threadIdx.x;
    int v = blkhist[t * NBKT + bin];
    s[t] = v;
    __syncthreads();
    #pragma unroll
    for (int off = 1; off < 256; off <<= 1) {
        int tv = (t >= off) ? s[t - off] : 0;
        __syncthreads();
        s[t] += tv;
        __syncthreads();
    }
    blkhist[t * NBKT + bin] = bucket_base[bin] + s[t] - v;  // absolute start
}

// ---------------------------------------------------------------- pass A3: scatter edges into buckets (packed)
__global__ __launch_bounds__(256) void bucket_scatter(const int* __restrict__ ei,
                                                      const int* __restrict__ blkhist,
                                                      unsigned* __restrict__ ebuf) {
    __shared__ int cur[NBKT];
    int b = blockIdx.x;
    for (int i = threadIdx.x; i < NBKT; i += 256) cur[i] = blkhist[b * NBKT + i];
    __syncthreads();
    int lo = b * CHUNK, hi = min(lo + CHUNK, NE);
    for (int e = lo + threadIdx.x; e < hi; e += 256) {
        int s = ei[e];
        int d = ei[NE + e];
        int pos = atomicAdd(&cur[d >> 7], 1);  // LDS atomic; block owns disjoint ranges
        ebuf[pos] = ((unsigned)(d & 127) << 16) | (unsigned)s;  // src < 2^16
    }
}

// ---------------------------------------------------------------- pass B: per-bucket CSR build
__global__ __launch_bounds__(128) void build_csr(const unsigned* __restrict__ ebuf,
                                                 const int* __restrict__ bucket_base,
                                                 int* __restrict__ rowoff,
                                                 int* __restrict__ csr_src,
                                                 float* __restrict__ dinv) {
    __shared__ int deg[128];
    __shared__ int loff[128];
    int g = blockIdx.x;
    int lo = bucket_base[g], hi = bucket_base[g + 1];
    int t = threadIdx.x;
    deg[t] = 0;
    __syncthreads();
    for (int p = lo + t; p < hi; p += 128)
        atomicAdd(&deg[ebuf[p] >> 16], 1);
    __syncthreads();
    int v = deg[t];
    loff[t] = v;
    __syncthreads();
    #pragma unroll
    for (int off = 1; off < 128; off <<= 1) {
        int tv = (t >= off) ? loff[t - off] : 0;
        __syncthreads();
        loff[t] += tv;
        __syncthreads();
    }
    int excl = loff[t] - v;
    int node = g * 128 + t;
    if (node < NN) {
        rowoff[node] = lo + excl;
        dinv[node] = 1.0f / sqrtf((float)v + 1.0f);
    }
    if (node == 0) rowoff[NN] = NE;
    deg[t] = lo + excl;  // reuse as cursor
    __syncthreads();
    for (int p = lo + t; p < hi; p += 128) {
        unsigned pk = ebuf[p];
        int pos = atomicAdd(&deg[pk >> 16], 1);
        csr_src[pos] = (int)(pk & 0xFFFFu);
    }
}

// ---------------------------------------------------------------- graph boundaries (batch is sorted)
__global__ __launch_bounds__(128) void bounds_kernel(const int* __restrict__ batch,
                                                     int* __restrict__ first) {
    int g = threadIdx.x;
    if (g <= NG) {
        int lo = 0, hi = NN;
        while (lo < hi) {
            int mid = (lo + hi) >> 1;
            if (batch[mid] < g) lo = mid + 1; else hi = mid;
        }
        first[g] = lo;  // lower_bound(batch, g)
    }
}

// ---------------------------------------------------------------- W prep: f32 [k][n] -> bf16 hi/lo transposed [n][k]
__global__ __launch_bounds__(256) void wprep_kernel(const float* __restrict__ W0,
                                                    const float* __restrict__ W1,
                                                    const float* __restrict__ W2,
                                                    short* __restrict__ out) {
    const float* W = (blockIdx.x == 0) ? W0 : (blockIdx.x == 1) ? W1 : W2;
    short* Wh = out + blockIdx.x * 2 * DIM * DIM;
    short* Wl = Wh + DIM * DIM;
    for (int idx = threadIdx.x; idx < DIM * DIM; idx += 256) {
        int k = idx >> 7, n = idx & 127;
        float v = W[idx];
        unsigned u = __float_as_uint(v);
        unsigned hb = (u + 0x7FFFu + ((u >> 16) & 1u)) & 0xFFFF0000u;  // RNE bf16
        float res = v - __uint_as_float(hb);
        unsigned u2 = __float_as_uint(res);
        unsigned lb = (u2 + 0x7FFFu + ((u2 >> 16) & 1u)) >> 16;
        Wh[n * DIM + k] = (short)(hb >> 16);
        Wl[n * DIM + k] = (short)lb;
    }
}

// ---------------------------------------------------------------- GEMM: Y = op(X) @ W via split-bf16 MFMA
// 3-term split: x*w = xh*wh + xl*wh + xh*wl  (al*bl dropped, ~2^-18 rel err)
#define WPAD 136  // LDS row stride in shorts
template <bool RELU>
__global__ __launch_bounds__(256) void gemm_mfma(const float* __restrict__ X,
                                                 const short* __restrict__ Wsp,
                                                 float* __restrict__ Y, int nrows) {
    __shared__ short Wh[DIM * WPAD];
    __shared__ short Wl[DIM * WPAD];
    int tid = threadIdx.x;
    {
        const short8* gh = (const short8*)Wsp;                // [n][k], 2048 short8
        const short8* gl = (const short8*)(Wsp + DIM * DIM);
        #pragma unroll
        for (int i = 0; i < 8; ++i) {
            int e = tid + 256 * i;        // short8 index
            int n = e >> 4;
            int k = (e & 15) * 8;
            *(short8*)&Wh[n * WPAD + k] = gh[e];
            *(short8*)&Wl[n * WPAD + k] = gl[e];
        }
    }
    int wave = tid >> 6;
    int lane = tid & 63;
    int lm = lane & 15;   // A row within tile / B col within tile / D col
    int lq = lane >> 4;   // k-octet selector / D row-quad
    int row0 = blockIdx.x * 64 + wave * 16;
    int rr = min(row0 + lm, nrows - 1);
    const float* Xp = X + (size_t)rr * DIM + lq * 8;

    float4v acc[8];
    #pragma unroll
    for (int i = 0; i < 8; ++i) acc[i] = (float4v){0.f, 0.f, 0.f, 0.f};

    __syncthreads();
    #pragma unroll
    for (int kk = 0; kk < 4; ++kk) {
        float4 xa = *(const float4*)(Xp + kk * 32);
        float4 xb = *(const float4*)(Xp + kk * 32 + 4);
        float xv[8] = {xa.x, xa.y, xa.z, xa.w, xb.x, xb.y, xb.z, xb.w};
        short8 ah, al;
        #pragma unroll
        for (int j = 0; j < 8; ++j) {
            float v = xv[j];
            if (RELU) v = fmaxf(v, 0.0f);
            unsigned u = __float_as_uint(v);
            unsigned hb = (u + 0x7FFFu + ((u >> 16) & 1u)) & 0xFFFF0000u;
            float res = v - __uint_as_float(hb);
            unsigned u2 = __float_as_uint(res);
            unsigned lb = (u2 + 0x7FFFu + ((u2 >> 16) & 1u)) >> 16;
            ah[j] = (short)(hb >> 16);
            al[j] = (short)lb;
        }
        #pragma unroll
        for (int n0 = 0; n0 < 8; ++n0) {
            short8 bh = *(const short8*)&Wh[(n0 * 16 + lm) * WPAD + kk * 32 + lq * 8];
            short8 bl = *(const short8*)&Wl[(n0 * 16 + lm) * WPAD + kk * 32 + lq * 8];
            acc[n0] = __builtin_amdgcn_mfma_f32_16x16x32_bf16(ah, bh, acc[n0], 0, 0, 0);
            acc[n0] = __builtin_amdgcn_mfma_f32_16x16x32_bf16(al, bh, acc[n0], 0, 0, 0);
            acc[n0] = __builtin_amdgcn_mfma_f32_16x16x32_bf16(ah, bl, acc[n0], 0, 0, 0);
        }
    }
    // D layout: col = lane&15, row = (lane>>4)*4 + reg  [verified m89/m91]
    #pragma unroll
    for (int n0 = 0; n0 < 8; ++n0) {
        #pragma unroll
        for (int rg = 0; rg < 4; ++rg) {
            int row = row0 + lq * 4 + rg;
            if (row < nrows) Y[(size_t)row * DIM + n0 * 16 + lm] = acc[n0][rg];
        }
    }
}

// ---------------------------------------------------------------- aggregation (CSR, 4 edge-groups x float4)
__global__ __launch_bounds__(128) void agg_kernel(const float* __restrict__ H,
                                                  float* __restrict__ O,
                                                  const int* __restrict__ rowoff,
                                                  const int* __restrict__ csr_src,
                                                  const float* __restrict__ dinv) {
    __shared__ float part[4][DIM];
    int i = blockIdx.x;
    int tid = threadIdx.x;
    int grp = tid >> 5, ln = tid & 31;
    int s = rowoff[i], e = rowoff[i + 1];
    const float* Hc = H + ln * 4;

    float4 a1 = make_float4(0.f, 0.f, 0.f, 0.f);
    float4 a2 = make_float4(0.f, 0.f, 0.f, 0.f);
    int p = s + grp;
    for (; p + 4 < e; p += 8) {
        int u1 = csr_src[p];
        int u2 = csr_src[p + 4];
        float d1 = dinv[u1];
        float d2 = dinv[u2];
        float4 h1 = *(const float4*)(Hc + (size_t)u1 * DIM);
        float4 h2 = *(const float4*)(Hc + (size_t)u2 * DIM);
        a1.x = fmaf(d1, h1.x, a1.x); a1.y = fmaf(d1, h1.y, a1.y);
        a1.z = fmaf(d1, h1.z, a1.z); a1.w = fmaf(d1, h1.w, a1.w);
        a2.x = fmaf(d2, h2.x, a2.x); a2.y = fmaf(d2, h2.y, a2.y);
        a2.z = fmaf(d2, h2.z, a2.z); a2.w = fmaf(d2, h2.w, a2.w);
    }
    if (p < e) {
        int u = csr_src[p];
        float d = dinv[u];
        float4 h = *(const float4*)(Hc + (size_t)u * DIM);
        a1.x = fmaf(d, h.x, a1.x); a1.y = fmaf(d, h.y, a1.y);
        a1.z = fmaf(d, h.z, a1.z); a1.w = fmaf(d, h.w, a1.w);
    }
    a1.x += a2.x; a1.y += a2.y; a1.z += a2.z; a1.w += a2.w;
    *(float4*)&part[grp][ln * 4] = a1;
    __syncthreads();
    // thread tid finalizes column tid
    float di = dinv[i];
    float tot = part[0][tid] + part[1][tid] + part[2][tid] + part[3][tid];
    tot = fmaf(di, H[(size_t)i * DIM + tid], tot);  // self-loop
    O[(size_t)i * DIM + tid] = di * tot;
}

// ---------------------------------------------------------------- pooling stage 1: per-(graph,slice) partials
__global__ __launch_bounds__(128) void pool_part(const float* __restrict__ H,
                                                 const int* __restrict__ first,
                                                 float* __restrict__ ppart) {
    __shared__ float part[4][DIM];
    int g = blockIdx.x;
    int sl = blockIdx.y;
    int tid = threadIdx.x;
    int rg = tid >> 5, ln = tid & 31;
    int s = first[g], e = first[g + 1];
    float4 acc = make_float4(0.f, 0.f, 0.f, 0.f);
    for (int r = s + sl * 4 + rg; r < e; r += PSLICE * 4) {
        float4 h = *(const float4*)(H + (size_t)r * DIM + ln * 4);
        acc.x += h.x; acc.y += h.y; acc.z += h.z; acc.w += h.w;
    }
    *(float4*)&part[rg][ln * 4] = acc;
    __syncthreads();
    float tot = part[0][tid] + part[1][tid] + part[2][tid] + part[3][tid];
    ppart[(size_t)(g * PSLICE + sl) * DIM + tid] = tot;
}

// ---------------------------------------------------------------- pooling stage 2: reduce slices, divide
__global__ __launch_bounds__(128) void pool_final(const float* __restrict__ ppart,
                                                  const int* __restrict__ first,
                                                  float* __restrict__ pooled) {
    int g = blockIdx.x;
    int j = threadIdx.x;
    float tot = 0.f;
    #pragma unroll
    for (int sl = 0; sl < PSLICE; ++sl)
        tot += ppart[(size_t)(g * PSLICE + sl) * DIM + j];
    float cnt = (float)max(first[g + 1] - first[g], 1);
    pooled[g * DIM + j] = tot / cnt;
}

// ---------------------------------------------------------------- final MLP
__global__ __launch_bounds__(128) void mlp_kernel(const float* __restrict__ pooled,
                                                  const float* __restrict__ M0w,
                                                  const float* __restrict__ M0b,
                                                  const float* __restrict__ M1w,
                                                  const float* __restrict__ M1b,
                                                  float* __restrict__ out) {
    __shared__ float p[DIM];
    __shared__ float t[DIM];
    int g = blockIdx.x;
    int j = threadIdx.x;
    p[j] = pooled[g * DIM + j];
    __syncthreads();
    float acc = M0b[j];
    #pragma unroll 8
    for (int k = 0; k < DIM; ++k) acc = fmaf(p[k], M0w[k * DIM + j], acc);
    t[j] = fmaxf(acc, 0.0f);
    __syncthreads();
    if (j < NOUT) {
        float o = M1b[j];
        #pragma unroll 8
        for (int k = 0; k < DIM; ++k) o = fmaf(t[k], M1w[k * NOUT + j], o);
        out[g * NOUT + j] = o;
    }
}

// ---------------------------------------------------------------- launcher
extern "C" void kernel_launch(void* const* d_in, const int* in_sizes, int n_in,
                              void* d_out, int out_size, void* d_ws, size_t ws_size,
                              hipStream_t stream) {
    const float* x   = (const float*)d_in[0];
    const float* W0  = (const float*)d_in[1];
    const float* W1  = (const float*)d_in[2];
    const float* W2  = (const float*)d_in[3];
    const float* M0w = (const float*)d_in[4];
    const float* M0b = (const float*)d_in[5];
    const float* M1w = (const float*)d_in[6];
    const float* M1b = (const float*)d_in[7];
    const int* ei    = (const int*)d_in[8];
    const int* batch = (const int*)d_in[9];
    float* out = (float*)d_out;

    char* ws = (char*)d_ws;
    size_t off = 0;
    auto take = [&](size_t bytes) -> void* {
        void* p = ws + off;
        off = (off + bytes + 255) & ~(size_t)255;
        return p;
    };
    float* hA    = (float*)take((size_t)NN * DIM * 4);
    float* hB    = (float*)take((size_t)NN * DIM * 4);
    unsigned* ebuf = (unsigned*)take((size_t)NE * 4);
    int* csr_src = (int*)take((size_t)NE * 4);
    int* blkhist = (int*)take((size_t)HBLK * NBKT * 4);
    int* bintot  = (int*)take((size_t)NBKT * 4);
    int* bucket_base = (int*)take((size_t)(NBKT + 1) * 4);
    int* rowoff  = (int*)take((size_t)(NN + 1) * 4);
    float* dinv  = (float*)take((size_t)NN * 4);
    int* first   = (int*)take((size_t)(NG + 1) * 4);
    float* ppart = (float*)take((size_t)NG * PSLICE * DIM * 4);
    float* pooled = (float*)take((size_t)NG * DIM * 4);
    short* wsp   = (short*)take((size_t)3 * 2 * DIM * DIM * 2);
    (void)ws_size; (void)in_sizes; (void)n_in; (void)out_size;

    // ---- weight split (bf16 hi/lo, transposed) + CSR build
    wprep_kernel<<<3, 256, 0, stream>>>(W0, W1, W2, wsp);
    hist_kernel<<<HBLK, 256, 0, stream>>>(ei, blkhist);
    bintot_kernel<<<NBKT, 256, 0, stream>>>(blkhist, bintot);
    base_scan_kernel<<<1, 512, 0, stream>>>(bintot, bucket_base);
    binoff_kernel<<<NBKT, 256, 0, stream>>>(blkhist, bucket_base);
    bucket_scatter<<<HBLK, 256, 0, stream>>>(ei, blkhist, ebuf);
    build_csr<<<NBKT, 128, 0, stream>>>(ebuf, bucket_base, rowoff, csr_src, dinv);
    bounds_kernel<<<1, 128, 0, stream>>>(batch, first);

    // ---- 3x (GEMM -> aggregate)
    const int GB = (NN + 63) / 64;
    gemm_mfma<false><<<GB, 256, 0, stream>>>(x, wsp, hA, NN);
    agg_kernel<<<NN, 128, 0, stream>>>(hA, hB, rowoff, csr_src, dinv);
    gemm_mfma<true><<<GB, 256, 0, stream>>>(hB, wsp + 2 * DIM * DIM, hA, NN);
    agg_kernel<<<NN, 128, 0, stream>>>(hA, hB, rowoff, csr_src, dinv);
    gemm_mfma<true><<<GB, 256, 0, stream>>>(hB, wsp + 4 * DIM * DIM, hA, NN);
    agg_kernel<<<NN, 128, 0, stream>>>(hA, hB, rowoff, csr_src, dinv);

    // ---- pool + MLP (atomic-free two-stage)
    dim3 pgrid(NG, PSLICE);
    pool_part<<<pgrid, 128, 0, stream>>>(hB, first, ppart);
    pool_final<<<NG, 128, 0, stream>>>(ppart, first, pooled);
    mlp_kernel<<<NG, 128, 0, stream>>>(pooled, M0w, M0b, M1w, M1b, out);
}

// Round 5
// 372.920 us; speedup vs baseline: 2.5172x; 1.0655x over previous
//
#include <hip/hip_runtime.h>

#define NN 50000      // nodes
#define NE 800000     // edges
#define DIM 128       // feature dim (D == H)
#define NG 64         // graphs
#define NOUT 10       // output dim

#define NBKT 391      // coarse buckets: ceil(NN/128), dst>>7
#define HBLK 256      // histogram/scatter blocks
#define CHUNK ((NE + HBLK - 1) / HBLK)   // 3125 edges per block
#define PSLICE 8      // pooling slices per graph

typedef __attribute__((ext_vector_type(8))) short short8;
typedef __attribute__((ext_vector_type(4))) float float4v;

// ---------------------------------------------------------------- pass A1: per-block bucket histogram
__global__ __launch_bounds__(256) void hist_kernel(const int* __restrict__ ei,
                                                   int* __restrict__ blkhist) {
    __shared__ int h[NBKT];
    int b = blockIdx.x;
    for (int i = threadIdx.x; i < NBKT; i += 256) h[i] = 0;
    __syncthreads();
    int lo = b * CHUNK, hi = min(lo + CHUNK, NE);
    for (int e = lo + threadIdx.x; e < hi; e += 256)
        atomicAdd(&h[ei[NE + e] >> 7], 1);  // LDS atomic
    __syncthreads();
    for (int i = threadIdx.x; i < NBKT; i += 256)
        blkhist[b * NBKT + i] = h[i];
}

// ---------------------------------------------------------------- pass A2a: bucket totals
__global__ __launch_bounds__(256) void bintot_kernel(const int* __restrict__ blkhist,
                                                     int* __restrict__ bintot) {
    __shared__ int s[256];
    int bin = blockIdx.x;
    int t = threadIdx.x;
    s[t] = blkhist[t * NBKT + bin];
    __syncthreads();
    #pragma unroll
    for (int off = 128; off > 0; off >>= 1) {
        if (t < off) s[t] += s[t + off];
        __syncthreads();
    }
    if (t == 0) bintot[bin] = s[0];
}

// ---------------------------------------------------------------- pass A2b: scan bucket totals -> bucket_base
__global__ __launch_bounds__(512) void base_scan_kernel(const int* __restrict__ bintot,
                                                        int* __restrict__ bucket_base) {
    __shared__ int s[512];
    int t = threadIdx.x;
    int v = (t < NBKT) ? bintot[t] : 0;
    s[t] = v;
    __syncthreads();
    #pragma unroll
    for (int off = 1; off < 512; off <<= 1) {
        int tv = (t >= off) ? s[t - off] : 0;
        __syncthreads();
        s[t] += tv;
        __syncthreads();
    }
    if (t <= NBKT) bucket_base[t] = s[t] - v;  // exclusive; t==NBKT -> NE
}

// ---------------------------------------------------------------- pass A2c: per-(bucket,block) absolute offsets
__global__ __launch_bounds__(256) void binoff_kernel(int* __restrict__ blkhist,
                                                     const int* __restrict__ bucket_base) {
    __shared__ int s[256];
    int bin = blockIdx.x;
    int t = threadIdx.x;
    int v = blkhist[t * NBKT + bin];
    s[t] = v;
    __syncthreads();
    #pragma unroll
    for (int off = 1; off < 256; off <<= 1) {
        int tv = (t >= off) ? s[t - off] : 0;
        __syncthreads();
        s[t] += tv;
        __syncthreads();
    }
    blkhist[t * NBKT + bin] = bucket_base[bin] + s[t] - v;  // absolute start
}

// ---------------------------------------------------------------- pass A3: scatter edges into buckets (packed)
__global__ __launch_bounds__(256) void bucket_scatter(const int* __restrict__ ei,
                                                      const int* __restrict__ blkhist,
                                                      unsigned* __restrict__ ebuf) {
    __shared__ int cur[NBKT];
    int b = blockIdx.x;
    for (int i = threadIdx.x; i < NBKT; i += 256) cur[i] = blkhist[b * NBKT + i];
    __syncthreads();
    int lo = b * CHUNK, hi = min(lo + CHUNK, NE);
    for (int e = lo + threadIdx.x; e < hi; e += 256) {
        int s = ei[e];
        int d = ei[NE + e];
        int pos = atomicAdd(&cur[d >> 7], 1);  // LDS atomic; block owns disjoint ranges
        ebuf[pos] = ((unsigned)(d & 127) << 16) | (unsigned)s;  // src < 2^16
    }
}

// ---------------------------------------------------------------- pass B: per-bucket CSR build
__global__ __launch_bounds__(128) void build_csr(const unsigned* __restrict__ ebuf,
                                                 const int* __restrict__ bucket_base,
                                                 int* __restrict__ rowoff,
                                                 int* __restrict__ csr_src,
                                                 float* __restrict__ dinv) {
    __shared__ int deg[128];
    __shared__ int loff[128];
    int g = blockIdx.x;
    int lo = bucket_base[g], hi = bucket_base[g + 1];
    int t = threadIdx.x;
    deg[t] = 0;
    __syncthreads();
    for (int p = lo + t; p < hi; p += 128)
        atomicAdd(&deg[ebuf[p] >> 16], 1);
    __syncthreads();
    int v = deg[t];
    loff[t] = v;
    __syncthreads();
    #pragma unroll
    for (int off = 1; off < 128; off <<= 1) {
        int tv = (t >= off) ? loff[t - off] : 0;
        __syncthreads();
        loff[t] += tv;
        __syncthreads();
    }
    int excl = loff[t] - v;
    int node = g * 128 + t;
    if (node < NN) {
        rowoff[node] = lo + excl;
        dinv[node] = 1.0f / sqrtf((float)v + 1.0f);
    }
    if (node == 0) rowoff[NN] = NE;
    deg[t] = lo + excl;  // reuse as cursor
    __syncthreads();
    for (int p = lo + t; p < hi; p += 128) {
        unsigned pk = ebuf[p];
        int pos = atomicAdd(&deg[pk >> 16], 1);
        csr_src[pos] = (int)(pk & 0xFFFFu);
    }
}

// ---------------------------------------------------------------- graph boundaries (batch is sorted)
__global__ __launch_bounds__(128) void bounds_kernel(const int* __restrict__ batch,
                                                     int* __restrict__ first) {
    int g = threadIdx.x;
    if (g <= NG) {
        int lo = 0, hi = NN;
        while (lo < hi) {
            int mid = (lo + hi) >> 1;
            if (batch[mid] < g) lo = mid + 1; else hi = mid;
        }
        first[g] = lo;  // lower_bound(batch, g)
    }
}

// ---------------------------------------------------------------- W prep: f32 [k][n] -> bf16 hi/lo transposed [n][k]
// grid = 48 blocks: blockIdx>>4 selects W, low 4 bits select a 1024-elem slice
__global__ __launch_bounds__(256) void wprep_kernel(const float* __restrict__ W0,
                                                    const float* __restrict__ W1,
                                                    const float* __restrict__ W2,
                                                    short* __restrict__ out) {
    int w = blockIdx.x >> 4;
    int sub = blockIdx.x & 15;
    const float* W = (w == 0) ? W0 : (w == 1) ? W1 : W2;
    short* Wh = out + w * 2 * DIM * DIM;
    short* Wl = Wh + DIM * DIM;
    #pragma unroll
    for (int t = 0; t < 4; ++t) {
        int idx = sub * 1024 + t * 256 + threadIdx.x;
        int k = idx >> 7, n = idx & 127;
        float v = W[idx];
        unsigned u = __float_as_uint(v);
        unsigned hb = (u + 0x7FFFu + ((u >> 16) & 1u)) & 0xFFFF0000u;  // RNE bf16
        float res = v - __uint_as_float(hb);
        unsigned u2 = __float_as_uint(res);
        unsigned lb = (u2 + 0x7FFFu + ((u2 >> 16) & 1u)) >> 16;
        Wh[n * DIM + k] = (short)(hb >> 16);
        Wl[n * DIM + k] = (short)lb;
    }
}

// ---------------------------------------------------------------- GEMM: Y = op(X) @ W via split-bf16 MFMA
// 3-term split: x*w = xh*wh + xl*wh + xh*wl  (al*bl dropped, ~2^-18 rel err)
#define WPAD 136  // LDS row stride in shorts
template <bool RELU>
__global__ __launch_bounds__(256) void gemm_mfma(const float* __restrict__ X,
                                                 const short* __restrict__ Wsp,
                                                 float* __restrict__ Y, int nrows) {
    __shared__ short Wh[DIM * WPAD];
    __shared__ short Wl[DIM * WPAD];
    int tid = threadIdx.x;
    {
        const short8* gh = (const short8*)Wsp;                // [n][k], 2048 short8
        const short8* gl = (const short8*)(Wsp + DIM * DIM);
        #pragma unroll
        for (int i = 0; i < 8; ++i) {
            int e = tid + 256 * i;        // short8 index
            int n = e >> 4;
            int k = (e & 15) * 8;
            *(short8*)&Wh[n * WPAD + k] = gh[e];
            *(short8*)&Wl[n * WPAD + k] = gl[e];
        }
    }
    int wave = tid >> 6;
    int lane = tid & 63;
    int lm = lane & 15;   // A row within tile / B col within tile / D col
    int lq = lane >> 4;   // k-octet selector / D row-quad
    int row0 = blockIdx.x * 64 + wave * 16;
    int rr = min(row0 + lm, nrows - 1);
    const float* Xp = X + (size_t)rr * DIM + lq * 8;

    float4v acc[8];
    #pragma unroll
    for (int i = 0; i < 8; ++i) acc[i] = (float4v){0.f, 0.f, 0.f, 0.f};

    __syncthreads();
    #pragma unroll
    for (int kk = 0; kk < 4; ++kk) {
        float4 xa = *(const float4*)(Xp + kk * 32);
        float4 xb = *(const float4*)(Xp + kk * 32 + 4);
        float xv[8] = {xa.x, xa.y, xa.z, xa.w, xb.x, xb.y, xb.z, xb.w};
        short8 ah, al;
        #pragma unroll
        for (int j = 0; j < 8; ++j) {
            float v = xv[j];
            if (RELU) v = fmaxf(v, 0.0f);
            unsigned u = __float_as_uint(v);
            unsigned hb = (u + 0x7FFFu + ((u >> 16) & 1u)) & 0xFFFF0000u;
            float res = v - __uint_as_float(hb);
            unsigned u2 = __float_as_uint(res);
            unsigned lb = (u2 + 0x7FFFu + ((u2 >> 16) & 1u)) >> 16;
            ah[j] = (short)(hb >> 16);
            al[j] = (short)lb;
        }
        #pragma unroll
        for (int n0 = 0; n0 < 8; ++n0) {
            short8 bh = *(const short8*)&Wh[(n0 * 16 + lm) * WPAD + kk * 32 + lq * 8];
            short8 bl = *(const short8*)&Wl[(n0 * 16 + lm) * WPAD + kk * 32 + lq * 8];
            acc[n0] = __builtin_amdgcn_mfma_f32_16x16x32_bf16(ah, bh, acc[n0], 0, 0, 0);
            acc[n0] = __builtin_amdgcn_mfma_f32_16x16x32_bf16(al, bh, acc[n0], 0, 0, 0);
            acc[n0] = __builtin_amdgcn_mfma_f32_16x16x32_bf16(ah, bl, acc[n0], 0, 0, 0);
        }
    }
    // D layout: col = lane&15, row = (lane>>4)*4 + reg  [verified m89/m91]
    #pragma unroll
    for (int n0 = 0; n0 < 8; ++n0) {
        #pragma unroll
        for (int rg = 0; rg < 4; ++rg) {
            int row = row0 + lq * 4 + rg;
            if (row < nrows) Y[(size_t)row * DIM + n0 * 16 + lm] = acc[n0][rg];
        }
    }
}

// ---------------------------------------------------------------- aggregation (CSR, 4 groups x 4-deep batched gathers)
__global__ __launch_bounds__(128) void agg_kernel(const float* __restrict__ H,
                                                  float* __restrict__ O,
                                                  const int* __restrict__ rowoff,
                                                  const int* __restrict__ csr_src,
                                                  const float* __restrict__ dinv) {
    __shared__ float part[4][DIM];
    int i = blockIdx.x;
    int tid = threadIdx.x;
    int grp = tid >> 5, ln = tid & 31;
    int s = rowoff[i], e = rowoff[i + 1];
    const float* Hc = H + ln * 4;

    float4 acc = make_float4(0.f, 0.f, 0.f, 0.f);
    int p = s + grp;
    // 4-deep: indices are wave-broadcast loads; 4 independent 512 B row gathers in flight
    for (; p + 12 < e; p += 16) {
        int u0 = csr_src[p];
        int u1 = csr_src[p + 4];
        int u2 = csr_src[p + 8];
        int u3 = csr_src[p + 12];
        float d0 = dinv[u0], d1 = dinv[u1], d2 = dinv[u2], d3 = dinv[u3];
        float4 h0 = *(const float4*)(Hc + (size_t)u0 * DIM);
        float4 h1 = *(const float4*)(Hc + (size_t)u1 * DIM);
        float4 h2 = *(const float4*)(Hc + (size_t)u2 * DIM);
        float4 h3 = *(const float4*)(Hc + (size_t)u3 * DIM);
        acc.x = fmaf(d0, h0.x, acc.x); acc.y = fmaf(d0, h0.y, acc.y);
        acc.z = fmaf(d0, h0.z, acc.z); acc.w = fmaf(d0, h0.w, acc.w);
        acc.x = fmaf(d1, h1.x, acc.x); acc.y = fmaf(d1, h1.y, acc.y);
        acc.z = fmaf(d1, h1.z, acc.z); acc.w = fmaf(d1, h1.w, acc.w);
        acc.x = fmaf(d2, h2.x, acc.x); acc.y = fmaf(d2, h2.y, acc.y);
        acc.z = fmaf(d2, h2.z, acc.z); acc.w = fmaf(d2, h2.w, acc.w);
        acc.x = fmaf(d3, h3.x, acc.x); acc.y = fmaf(d3, h3.y, acc.y);
        acc.z = fmaf(d3, h3.z, acc.z); acc.w = fmaf(d3, h3.w, acc.w);
    }
    for (; p < e; p += 4) {
        int u = csr_src[p];
        float d = dinv[u];
        float4 h = *(const float4*)(Hc + (size_t)u * DIM);
        acc.x = fmaf(d, h.x, acc.x); acc.y = fmaf(d, h.y, acc.y);
        acc.z = fmaf(d, h.z, acc.z); acc.w = fmaf(d, h.w, acc.w);
    }
    *(float4*)&part[grp][ln * 4] = acc;
    __syncthreads();
    // thread tid finalizes column tid
    float di = dinv[i];
    float tot = part[0][tid] + part[1][tid] + part[2][tid] + part[3][tid];
    tot = fmaf(di, H[(size_t)i * DIM + tid], tot);  // self-loop
    O[(size_t)i * DIM + tid] = di * tot;
}

// ---------------------------------------------------------------- pooling stage 1: per-(graph,slice) partials
__global__ __launch_bounds__(128) void pool_part(const float* __restrict__ H,
                                                 const int* __restrict__ first,
                                                 float* __restrict__ ppart) {
    __shared__ float part[4][DIM];
    int g = blockIdx.x;
    int sl = blockIdx.y;
    int tid = threadIdx.x;
    int rg = tid >> 5, ln = tid & 31;
    int s = first[g], e = first[g + 1];
    float4 acc = make_float4(0.f, 0.f, 0.f, 0.f);
    for (int r = s + sl * 4 + rg; r < e; r += PSLICE * 4) {
        float4 h = *(const float4*)(H + (size_t)r * DIM + ln * 4);
        acc.x += h.x; acc.y += h.y; acc.z += h.z; acc.w += h.w;
    }
    *(float4*)&part[rg][ln * 4] = acc;
    __syncthreads();
    float tot = part[0][tid] + part[1][tid] + part[2][tid] + part[3][tid];
    ppart[(size_t)(g * PSLICE + sl) * DIM + tid] = tot;
}

// ---------------------------------------------------------------- pool reduce + MLP (fused)
__global__ __launch_bounds__(128) void mlp_kernel(const float* __restrict__ ppart,
                                                  const int* __restrict__ first,
                                                  const float* __restrict__ M0w,
                                                  const float* __restrict__ M0b,
                                                  const float* __restrict__ M1w,
                                                  const float* __restrict__ M1b,
                                                  float* __restrict__ out) {
    __shared__ float p[DIM];
    __shared__ float t[DIM];
    int g = blockIdx.x;
    int j = threadIdx.x;
    float tot = 0.f;
    #pragma unroll
    for (int sl = 0; sl < PSLICE; ++sl)
        tot += ppart[(size_t)(g * PSLICE + sl) * DIM + j];
    float cnt = (float)max(first[g + 1] - first[g], 1);
    p[j] = tot / cnt;
    __syncthreads();
    float acc = M0b[j];
    #pragma unroll 8
    for (int k = 0; k < DIM; ++k) acc = fmaf(p[k], M0w[k * DIM + j], acc);
    t[j] = fmaxf(acc, 0.0f);
    __syncthreads();
    if (j < NOUT) {
        float o = M1b[j];
        #pragma unroll 8
        for (int k = 0; k < DIM; ++k) o = fmaf(t[k], M1w[k * NOUT + j], o);
        out[g * NOUT + j] = o;
    }
}

// ---------------------------------------------------------------- launcher
extern "C" void kernel_launch(void* const* d_in, const int* in_sizes, int n_in,
                              void* d_out, int out_size, void* d_ws, size_t ws_size,
                              hipStream_t stream) {
    const float* x   = (const float*)d_in[0];
    const float* W0  = (const float*)d_in[1];
    const float* W1  = (const float*)d_in[2];
    const float* W2  = (const float*)d_in[3];
    const float* M0w = (const float*)d_in[4];
    const float* M0b = (const float*)d_in[5];
    const float* M1w = (const float*)d_in[6];
    const float* M1b = (const float*)d_in[7];
    const int* ei    = (const int*)d_in[8];
    const int* batch = (const int*)d_in[9];
    float* out = (float*)d_out;

    char* ws = (char*)d_ws;
    size_t off = 0;
    auto take = [&](size_t bytes) -> void* {
        void* p = ws + off;
        off = (off + bytes + 255) & ~(size_t)255;
        return p;
    };
    float* hA    = (float*)take((size_t)NN * DIM * 4);
    float* hB    = (float*)take((size_t)NN * DIM * 4);
    unsigned* ebuf = (unsigned*)take((size_t)NE * 4);
    int* csr_src = (int*)take((size_t)NE * 4);
    int* blkhist = (int*)take((size_t)HBLK * NBKT * 4);
    int* bintot  = (int*)take((size_t)NBKT * 4);
    int* bucket_base = (int*)take((size_t)(NBKT + 1) * 4);
    int* rowoff  = (int*)take((size_t)(NN + 1) * 4);
    float* dinv  = (float*)take((size_t)NN * 4);
    int* first   = (int*)take((size_t)(NG + 1) * 4);
    float* ppart = (float*)take((size_t)NG * PSLICE * DIM * 4);
    short* wsp   = (short*)take((size_t)3 * 2 * DIM * DIM * 2);
    (void)ws_size; (void)in_sizes; (void)n_in; (void)out_size;

    // ---- weight split (bf16 hi/lo, transposed) + CSR build
    wprep_kernel<<<48, 256, 0, stream>>>(W0, W1, W2, wsp);
    hist_kernel<<<HBLK, 256, 0, stream>>>(ei, blkhist);
    bintot_kernel<<<NBKT, 256, 0, stream>>>(blkhist, bintot);
    base_scan_kernel<<<1, 512, 0, stream>>>(bintot, bucket_base);
    binoff_kernel<<<NBKT, 256, 0, stream>>>(blkhist, bucket_base);
    bucket_scatter<<<HBLK, 256, 0, stream>>>(ei, blkhist, ebuf);
    build_csr<<<NBKT, 128, 0, stream>>>(ebuf, bucket_base, rowoff, csr_src, dinv);
    bounds_kernel<<<1, 128, 0, stream>>>(batch, first);

    // ---- 3x (GEMM -> aggregate)
    const int GB = (NN + 63) / 64;
    gemm_mfma<false><<<GB, 256, 0, stream>>>(x, wsp, hA, NN);
    agg_kernel<<<NN, 128, 0, stream>>>(hA, hB, rowoff, csr_src, dinv);
    gemm_mfma<true><<<GB, 256, 0, stream>>>(hB, wsp + 2 * DIM * DIM, hA, NN);
    agg_kernel<<<NN, 128, 0, stream>>>(hA, hB, rowoff, csr_src, dinv);
    gemm_mfma<true><<<GB, 256, 0, stream>>>(hB, wsp + 4 * DIM * DIM, hA, NN);
    agg_kernel<<<NN, 128, 0, stream>>>(hA, hB, rowoff, csr_src, dinv);

    // ---- pool + MLP (atomic-free two-stage, stage 2 fused into MLP)
    dim3 pgrid(NG, PSLICE);
    pool_part<<<pgrid, 128, 0, stream>>>(hB, first, ppart);
    mlp_kernel<<<NG, 128, 0, stream>>>(ppart, first, M0w, M0b, M1w, M1b, out);
}